// Round 1
// baseline (153.940 us; speedup 1.0000x reference)
//
#include <hip/hip_runtime.h>
#include <hip/hip_bf16.h>

// out[b,s,h] = word_emb[input_ids[b,s]][h] + type_emb[token_type_ids[b,s]][h] + pos_emb[s][h]
// H = 768 floats = 192 float4 per row. One wave (64 lanes) per token; each
// lane handles 3 float4 (48 B) -> fully coalesced 3072 B row read/write.

#define HIDDEN4 192   // 768 / 4
#define SEQ     512

__global__ __launch_bounds__(256) void BertEmbedding_77670188581156_kernel(
    const int* __restrict__ input_ids,
    const int* __restrict__ token_type_ids,
    const float4* __restrict__ word_emb,
    const float4* __restrict__ pos_emb,
    const float4* __restrict__ type_emb,
    float4* __restrict__ out,
    int n_tokens) {
    const int wave  = (blockIdx.x * blockDim.x + threadIdx.x) >> 6;  // token index
    const int lane  = threadIdx.x & 63;
    if (wave >= n_tokens) return;

    const int token = wave;
    const int id  = input_ids[token];       // wave-uniform broadcast load
    const int tt  = token_type_ids[token];
    const int s   = token & (SEQ - 1);      // position within sequence

    const float4* __restrict__ wrow = word_emb + (size_t)id * HIDDEN4;
    const float4* __restrict__ prow = pos_emb  + (size_t)s  * HIDDEN4;
    const float4* __restrict__ trow = type_emb + (size_t)tt * HIDDEN4;
    float4* __restrict__ orow       = out      + (size_t)token * HIDDEN4;

#pragma unroll
    for (int j = 0; j < 3; ++j) {
        const int h = j * 64 + lane;
        const float4 w = wrow[h];
        const float4 p = prow[h];
        const float4 t = trow[h];
        float4 r;
        r.x = w.x + p.x + t.x;
        r.y = w.y + p.y + t.y;
        r.z = w.z + p.z + t.z;
        r.w = w.w + p.w + t.w;
        orow[h] = r;
    }
}

extern "C" void kernel_launch(void* const* d_in, const int* in_sizes, int n_in,
                              void* d_out, int out_size, void* d_ws, size_t ws_size,
                              hipStream_t stream) {
    const int*    input_ids      = (const int*)d_in[0];
    const int*    token_type_ids = (const int*)d_in[1];
    const float4* word_emb       = (const float4*)d_in[2];
    const float4* pos_emb        = (const float4*)d_in[3];
    const float4* type_emb       = (const float4*)d_in[4];
    float4*       out            = (float4*)d_out;

    const int n_tokens = in_sizes[0];            // 32 * 512 = 16384
    const int waves_per_block = 256 / 64;        // 4 tokens per block
    const int grid = (n_tokens + waves_per_block - 1) / waves_per_block;

    BertEmbedding_77670188581156_kernel<<<grid, 256, 0, stream>>>(
        input_ids, token_type_ids, word_emb, pos_emb, type_emb, out, n_tokens);
}